// Round 10
// baseline (238.864 us; speedup 1.0000x reference)
//
#include <hip/hip_runtime.h>
#include <math.h>

#define D 64
#define S 64
#define BSZ 512
#define LTW 2016
#define ZROW 6112
#define OUT0_SIZE (BSZ * S * D)   // 2097152 floats
#define ZADJ_OFF  OUT0_SIZE

typedef float    f32x4 __attribute__((ext_vector_type(4)));
typedef _Float16 f16x8 __attribute__((ext_vector_type(8)));
typedef _Float16 f16x2 __attribute__((ext_vector_type(2)));

union V8 { f16x8 v; f16x2 h2[4]; uint4 u; };

__device__ __forceinline__ f16x2 pkrtz(float a, float b) {
    return __builtin_bit_cast(f16x2, __builtin_amdgcn_cvt_pkrtz(a, b));
}
__device__ __forceinline__ f16x8 relu8(f16x8 a) {
#if __has_builtin(__builtin_elementwise_max)
    return __builtin_elementwise_max(a, (f16x8)0);   // v_pk_max_f16 x4
#else
    f16x8 r;
#pragma unroll
    for (int i = 0; i < 8; ++i) r[i] = a[i] > (_Float16)0 ? a[i] : (_Float16)0;
    return r;
#endif
}

// ---------------------------------------------------------------------------
// k_zadjprep: blocks 0..255 -> z_adj (s = blk>>2, jt = blk&3), plus
//             transposed zadjT[s][j][i] when zt != nullptr.
//             blocks 256..319 -> fragment prep for channel c = blk-256.
// ---------------------------------------------------------------------------
__global__ __launch_bounds__(256) void k_zadjprep(
    const float* __restrict__ z, float* __restrict__ zadj,
    float* __restrict__ zt,
    const float* __restrict__ x,
    const float* __restrict__ W0, const float* __restrict__ W1,
    const float* __restrict__ W2,
    uint4* __restrict__ w0f, uint4* __restrict__ w1f,
    uint4* __restrict__ w2f, uint4* __restrict__ xf) {
    __shared__ float zp[4096];
    __shared__ float zlt[4160];   // 64 x 65 (padded)
    __shared__ float T[1280];     // 64 x 20 (16 used, padded)
    const int blk = blockIdx.x;
    const int tid = threadIdx.x;

    if (blk < 256) {
        const int s = blk >> 2, jt = blk & 3;
        const float* zs = z + (size_t)s * ZROW;
        const f32x4 zero4 = {0.0f, 0.0f, 0.0f, 0.0f};
#pragma unroll
        for (int rep = 0; rep < 4; ++rep) {
            int idx = (tid + rep * 256) * 4;
            *(f32x4*)&zp[idx] = *(const f32x4*)&zs[LTW + idx];   // dwordx4
            *(f32x4*)&zlt[idx] = zero4;
        }
        if (tid < 16) *(f32x4*)&zlt[4096 + tid * 4] = zero4;
        __syncthreads();
        for (int k = tid; k < LTW; k += 256) {
            float kf = (float)k;
            int r = (int)((1.0f + sqrtf(1.0f + 8.0f * kf)) * 0.5f);
            while (r * (r - 1) / 2 > k) --r;
            while ((r + 1) * r / 2 <= k) ++r;
            int t = k - r * (r - 1) / 2;
            zlt[r * 65 + t] = zs[k];
        }
        __syncthreads();
        // stage 1: T[r][jj] = sum_t zlt[r][t] * zp[t][jt*16+jj], 4 jj/thread
        const int rr = tid & 63, wj = (tid >> 6) * 4;
        {
            f32x4 acc = {0.0f, 0.0f, 0.0f, 0.0f};
#pragma unroll 8
            for (int t = 0; t < 64; ++t) {
                float zl = zlt[rr * 65 + t];                       // 2-way, free
                f32x4 zpv = *(const f32x4*)&zp[t * 64 + jt * 16 + wj]; // bcast
#pragma unroll
                for (int q = 0; q < 4; ++q) acc[q] = fmaf(zl, zpv[q], acc[q]);
            }
            *(f32x4*)&T[rr * 20 + wj] = acc;
        }
        __syncthreads();
        // stage 2: zadj[i][j] = sum_r zp[r][i] * T[r][jj], 4 jj/thread
        {
            const int i = rr;
            f32x4 acc = {0.0f, 0.0f, 0.0f, 0.0f};
#pragma unroll 8
            for (int r = 0; r < 64; ++r) {
                float zv = zp[r * 64 + i];                         // 2-way, free
                f32x4 tv = *(const f32x4*)&T[r * 20 + wj];         // bcast
#pragma unroll
                for (int q = 0; q < 4; ++q) acc[q] = fmaf(zv, tv[q], acc[q]);
            }
            *(f32x4*)&zadj[(size_t)s * 4096 + i * 64 + jt * 16 + wj] = acc;
            if (zt) {
#pragma unroll
                for (int q = 0; q < 4; ++q)
                    zt[(size_t)s * 4096 + (jt * 16 + wj + q) * 64 + i] = acc[q];
            }
        }
    } else {
        const int c = blk - 256;
        const int sl = tid >> 6, ln = tid & 63;
        const int q = ln >> 4, l15 = ln & 15;
        // --- W0 A-frags (16x16x32 f16): A[m][k=ks*32+q*8+j]
        {
            int Mt = sl >> 1, ks = sl & 1;
            const float* src = W0 + c * 2048 + (Mt * 16 + l15) * 64 + ks * 32 + q * 8;
            V8 hv;
#pragma unroll
            for (int j = 0; j < 8; ++j) hv.v[j] = (_Float16)src[j];
            w0f[(size_t)(c * 4 + sl) * 64 + ln] = hv.u;
        }
        // --- W1/W2 A-frags (16x16x32 f16, PERMUTED K): slot j -> k=(j>>2)*16+q*4+(j&3)
        {
            const float* Wsrc = (sl < 2) ? W1 : W2;
            uint4* dstb = (sl < 2) ? w1f : w2f;
            int Mt = sl & 1;
            const float* srow = Wsrc + c * 1024 + (Mt * 16 + l15) * 32;
            V8 hv;
#pragma unroll
            for (int j = 0; j < 8; ++j) {
                int k = ((j >> 2) << 4) + q * 4 + (j & 3);
                hv.v[j] = (_Float16)srow[k];
            }
            dstb[(size_t)(c * 2 + Mt) * 64 + ln] = hv.u;
        }
        // --- x B-frags (16x16x32 f16): B[k=ks*32+q*8+j][n=bt*16+l15]
        if (tid < 64) {
            int f = c * 64 + tid;
            int fln = f & 63, ks = (f >> 6) & 1, bt = f >> 7;
            int n = bt * 16 + (fln & 15), i0 = ks * 32 + (fln >> 4) * 8;
            const float* src = x + n * 64 + i0;
            V8 hv;
#pragma unroll
            for (int j = 0; j < 8; ++j) hv.v[j] = (_Float16)src[j];
            xf[f] = hv.u;
        }
    }
}

// ---------------------------------------------------------------------------
// k_main_mfma: fused 4-layer per-channel MLP. Grid (bh=2, c=64, sg=16);
// ALL global loads (weights, x-frags, biases, 4 s of z) hoisted to the
// prologue -> the s-loop is pure MFMA+VALU+store. 8 MFMA/Nt, in-lane
// transitions. Stores go to outT (s,c,b) — coalesced 256B/wave; the
// (b,s,c) layout is produced by k_outT. (Round-9 direct scatter store
// was 5x write-amplified and serialized the TA — do not repeat.)
// ---------------------------------------------------------------------------
template <bool ZT>
__global__ __launch_bounds__(256, 4) void k_main_mfma(
    const uint4* __restrict__ xf, const uint4* __restrict__ w0f,
    const uint4* __restrict__ w1f, const uint4* __restrict__ w2f,
    const float* __restrict__ zadj, const float* __restrict__ zadjT,
    const float* __restrict__ B0, const float* __restrict__ B1,
    const float* __restrict__ B2, const float* __restrict__ W3,
    const float* __restrict__ B3, float* __restrict__ outT) {
    const int bh = blockIdx.x;              // b-half (256 b's)
    const int c = blockIdx.y, sg = blockIdx.z;
    const int tid = threadIdx.x;
    const int wave = tid >> 6, lane = tid & 63;
    const int quad = lane >> 4;
    const int btbase = bh * 16 + wave * 4;  // 16-wide b-tiles

    // ---- hoisted channel weights
    V8 a0[2][2];                             // [Mt][ks]
#pragma unroll
    for (int Mt = 0; Mt < 2; ++Mt)
#pragma unroll
        for (int ks = 0; ks < 2; ++ks)
            a0[Mt][ks].u = w0f[(size_t)(c * 4 + Mt * 2 + ks) * 64 + lane];
    V8 a1[2], a2[2];                         // [Mt], permuted-K
#pragma unroll
    for (int Mt = 0; Mt < 2; ++Mt) {
        a1[Mt].u = w1f[(size_t)(c * 2 + Mt) * 64 + lane];
        a2[Mt].u = w2f[(size_t)(c * 2 + Mt) * 64 + lane];
    }
    // ---- hoisted x fragments (s-invariant)
    V8 xv[4][2];                             // [Nt][ks]
#pragma unroll
    for (int Nt = 0; Nt < 4; ++Nt)
#pragma unroll
        for (int ks = 0; ks < 2; ++ks)
            xv[Nt][ks].u = xf[(size_t)((btbase + Nt) * 2 + ks) * 64 + lane];
    // ---- biases / w3 (per-lane rows o = Mt*16 + quad*4 + r)
    f32x4 b0v[2], b1v[2], b2v[2], w3v[2];
#pragma unroll
    for (int Mt = 0; Mt < 2; ++Mt) {
        int off = c * 32 + Mt * 16 + quad * 4;
        b0v[Mt] = *(const f32x4*)(B0 + off);
        b1v[Mt] = *(const f32x4*)(B1 + off);
        b2v[Mt] = *(const f32x4*)(B2 + off);
        w3v[Mt] = *(const f32x4*)(W3 + off);
    }
    const float b3v = B3[c];

    // ---- hoist ALL 4 s of z: load (overlapped) then cvt to f16 pairs
    f16x2 zvh[4][2][4];                      // [it][ks][t]
#pragma unroll
    for (int it = 0; it < 4; ++it) {
        const int s = sg * 4 + it;
        if (ZT) {
            const f32x4* ztp = (const f32x4*)(zadjT + (size_t)s * 4096 + c * 64);
            f32x4 zq0 = ztp[quad * 2];
            f32x4 zq1 = ztp[quad * 2 + 1];
            f32x4 zq2 = ztp[8 + quad * 2];
            f32x4 zq3 = ztp[8 + quad * 2 + 1];
            zvh[it][0][0] = pkrtz(zq0[0], zq0[1]);
            zvh[it][0][1] = pkrtz(zq0[2], zq0[3]);
            zvh[it][0][2] = pkrtz(zq1[0], zq1[1]);
            zvh[it][0][3] = pkrtz(zq1[2], zq1[3]);
            zvh[it][1][0] = pkrtz(zq2[0], zq2[1]);
            zvh[it][1][1] = pkrtz(zq2[2], zq2[3]);
            zvh[it][1][2] = pkrtz(zq3[0], zq3[1]);
            zvh[it][1][3] = pkrtz(zq3[2], zq3[3]);
        } else {
#pragma unroll
            for (int ks = 0; ks < 2; ++ks) {
                const float* zp = zadj + (size_t)s * 4096 + (ks * 32 + quad * 8) * 64 + c;
                float zv[8];
#pragma unroll
                for (int j = 0; j < 8; ++j) zv[j] = zp[j * 64];
#pragma unroll
                for (int t = 0; t < 4; ++t)
                    zvh[it][ks][t] = pkrtz(zv[2 * t], zv[2 * t + 1]);
            }
        }
    }

#pragma unroll 1
    for (int it = 0; it < 4; ++it) {
        const int s = sg * 4 + it;
        // ---- scale layer-0 A by z (A[m][k] *= z[k])
        V8 a0s[2][2];
#pragma unroll
        for (int Mt = 0; Mt < 2; ++Mt)
#pragma unroll
            for (int ks = 0; ks < 2; ++ks)
#pragma unroll
                for (int t = 0; t < 4; ++t)
                    a0s[Mt][ks].h2[t] = a0[Mt][ks].h2[t] * zvh[it][ks][t];

        float red[4];
#pragma unroll
        for (int Nt = 0; Nt < 4; ++Nt) {
            // ---------- layer 0 ----------
            f32x4 acc0[2] = {b0v[0], b0v[1]};
#pragma unroll
            for (int ks = 0; ks < 2; ++ks)
#pragma unroll
                for (int Mt = 0; Mt < 2; ++Mt)
                    acc0[Mt] = __builtin_amdgcn_mfma_f32_16x16x32_f16(
                        a0s[Mt][ks].v, xv[Nt][ks].v, acc0[Mt], 0, 0, 0);
            // ---------- transition 0->1 (pkrtz then packed relu) ----------
            V8 bb;
            bb.h2[0] = pkrtz(acc0[0][0], acc0[0][1]);
            bb.h2[1] = pkrtz(acc0[0][2], acc0[0][3]);
            bb.h2[2] = pkrtz(acc0[1][0], acc0[1][1]);
            bb.h2[3] = pkrtz(acc0[1][2], acc0[1][3]);
            bb.v = relu8(bb.v);
            // ---------- layer 1 ----------
            f32x4 acc1[2] = {b1v[0], b1v[1]};
#pragma unroll
            for (int Mt = 0; Mt < 2; ++Mt)
                acc1[Mt] = __builtin_amdgcn_mfma_f32_16x16x32_f16(
                    a1[Mt].v, bb.v, acc1[Mt], 0, 0, 0);
            // ---------- transition 1->2 ----------
            V8 cc;
            cc.h2[0] = pkrtz(acc1[0][0], acc1[0][1]);
            cc.h2[1] = pkrtz(acc1[0][2], acc1[0][3]);
            cc.h2[2] = pkrtz(acc1[1][0], acc1[1][1]);
            cc.h2[3] = pkrtz(acc1[1][2], acc1[1][3]);
            cc.v = relu8(cc.v);
            // ---------- layer 2 ----------
            f32x4 acc2[2] = {b2v[0], b2v[1]};
#pragma unroll
            for (int Mt = 0; Mt < 2; ++Mt)
                acc2[Mt] = __builtin_amdgcn_mfma_f32_16x16x32_f16(
                    a2[Mt].v, cc.v, acc2[Mt], 0, 0, 0);
            // ---------- layer 3 partial: relu(acc2) . w3 ----------
            float p = 0.0f;
#pragma unroll
            for (int Mt = 0; Mt < 2; ++Mt)
#pragma unroll
                for (int r = 0; r < 4; ++r)
                    p = fmaf(w3v[Mt][r], fmaxf(acc2[Mt][r], 0.0f), p);
            p += __shfl_xor(p, 16, 64);
            p += __shfl_xor(p, 32, 64);
            red[Nt] = p;
        }
        float outv = (quad & 2) ? ((quad & 1) ? red[3] : red[2])
                                : ((quad & 1) ? red[1] : red[0]);
        outv += b3v;
        // coalesced 256B per wave into outT (s,c,b)
        outT[((size_t)s * 64 + c) * 512 + bh * 256 + tid] = outv;
    }
}

// ---------------------------------------------------------------------------
// Fallback VALU kernel (round-2 proven path).
// ---------------------------------------------------------------------------
__global__ __launch_bounds__(256, 3) void k_main_valu(
    const float* __restrict__ xsrc, const float* __restrict__ zadj,
    const float* __restrict__ W0, const float* __restrict__ B0,
    const float* __restrict__ W1, const float* __restrict__ B1,
    const float* __restrict__ W2, const float* __restrict__ B2,
    const float* __restrict__ W3, const float* __restrict__ B3,
    float* __restrict__ outp, int o_sS, int o_cS, int o_bS) {
    const int c = blockIdx.x;
    const int s = blockIdx.y;
    const int lane = threadIdx.x & 63;
    const int wave = threadIdx.x >> 6;

    const float* w0c = W0 + c * 2048;
    const float* w1c = W1 + c * 1024;
    const float* w2c = W2 + c * 1024;
    const float* w3c = W3 + c * 32;
    const float* b0c = B0 + c * 32;
    const float* b1c = B1 + c * 32;
    const float* b2c = B2 + c * 32;
    const float b3v = B3[c];
    const float* zc = zadj + s * 4096 + c;

#pragma unroll 1
    for (int bc = 0; bc < 2; ++bc) {
        const int b = wave * 128 + bc * 64 + lane;
        float h1[32], h2[32];
#pragma unroll
        for (int o = 0; o < 32; ++o) h1[o] = b0c[o];
#pragma unroll 8
        for (int i = 0; i < 64; ++i) {
            float hi = zc[i * 64] * xsrc[b * 64 + i];
#pragma unroll
            for (int o = 0; o < 32; ++o) h1[o] = fmaf(w0c[o * 64 + i], hi, h1[o]);
        }
#pragma unroll
        for (int o = 0; o < 32; ++o) { h1[o] = fmaxf(h1[o], 0.0f); h2[o] = b1c[o]; }
#pragma unroll 8
        for (int j = 0; j < 32; ++j) {
            float v = h1[j];
#pragma unroll
            for (int o = 0; o < 32; ++o) h2[o] = fmaf(w1c[o * 32 + j], v, h2[o]);
        }
#pragma unroll
        for (int o = 0; o < 32; ++o) { h2[o] = fmaxf(h2[o], 0.0f); h1[o] = b2c[o]; }
#pragma unroll 8
        for (int j = 0; j < 32; ++j) {
            float v = h2[j];
#pragma unroll
            for (int o = 0; o < 32; ++o) h1[o] = fmaf(w2c[o * 32 + j], v, h1[o]);
        }
        float a = b3v;
#pragma unroll
        for (int j = 0; j < 32; ++j) a = fmaf(w3c[j], fmaxf(h1[j], 0.0f), a);
        outp[s * o_sS + c * o_cS + b * o_bS] = a;
    }
}

// ---------------------------------------------------------------------------
// k_outT: transpose outT (s,c,b) -> out (b,s,c). dwordx4 global both sides.
// ---------------------------------------------------------------------------
__global__ __launch_bounds__(256) void k_outT(const float* __restrict__ outT,
                                              float* __restrict__ out) {
    __shared__ float tile[64 * 65];
    const int bt = blockIdx.x;   // 8 b-tiles
    const int s = blockIdx.y;    // 64
    const int tid = threadIdx.x;
    const int r16 = tid >> 4, q4 = (tid & 15) * 4;
#pragma unroll
    for (int rep = 0; rep < 4; ++rep) {
        int crow = rep * 16 + r16;
        f32x4 v = *(const f32x4*)&outT[(s * 64 + crow) * 512 + bt * 64 + q4];
#pragma unroll
        for (int i = 0; i < 4; ++i) tile[crow * 65 + q4 + i] = v[i];
    }
    __syncthreads();
#pragma unroll
    for (int rep = 0; rep < 4; ++rep) {
        int brow = rep * 16 + r16;
        f32x4 v;
#pragma unroll
        for (int i = 0; i < 4; ++i) v[i] = tile[(q4 + i) * 65 + brow];
        *(f32x4*)&out[(bt * 64 + brow) * 4096 + s * 64 + q4] = v;
    }
}

extern "C" void kernel_launch(void* const* d_in, const int* in_sizes, int n_in,
                              void* d_out, int out_size, void* d_ws, size_t ws_size,
                              hipStream_t stream) {
    const float* x  = (const float*)d_in[0];
    const float* z  = (const float*)d_in[1];
    const float* W0 = (const float*)d_in[2];
    const float* B0 = (const float*)d_in[3];
    const float* W1 = (const float*)d_in[4];
    const float* B1 = (const float*)d_in[5];
    const float* W2 = (const float*)d_in[6];
    const float* B2 = (const float*)d_in[7];
    const float* W3 = (const float*)d_in[8];
    const float* B3 = (const float*)d_in[9];

    float* out  = (float*)d_out;
    float* zadj = out + ZADJ_OFF;

    // workspace: outT | xf | w0f | w1f | w2f | zadjT
    const size_t OT_B  = (size_t)S * D * BSZ * sizeof(float); // 8388608
    const size_t XF_B  = 4096 * 16;                           // 65536
    const size_t W0F_B = (size_t)64 * 4 * 64 * 16;            // 262144
    const size_t W1F_B = (size_t)64 * 2 * 64 * 16;            // 131072
    const size_t W2F_B = W1F_B;
    const size_t ZT_B  = (size_t)S * 4096 * sizeof(float);    // 1048576
    const size_t FRAG_END = OT_B + XF_B + W0F_B + W1F_B + W2F_B;
    const bool has_oT   = ws_size >= OT_B;
    const bool has_frag = ws_size >= FRAG_END;
    const bool has_zt   = ws_size >= FRAG_END + ZT_B;

    char* wsb = (char*)d_ws;
    float* outT  = (float*)wsb;
    uint4* xf    = (uint4*)(wsb + OT_B);
    uint4* w0f   = (uint4*)(wsb + OT_B + XF_B);
    uint4* w1f   = (uint4*)(wsb + OT_B + XF_B + W0F_B);
    uint4* w2f   = (uint4*)(wsb + OT_B + XF_B + W0F_B + W1F_B);
    float* zadjT = (float*)(wsb + FRAG_END);

    if (has_frag) {
        hipLaunchKernelGGL(k_zadjprep, dim3(320), dim3(256), 0, stream,
                           z, zadj, has_zt ? zadjT : (float*)nullptr,
                           x, W0, W1, W2, w0f, w1f, w2f, xf);
        if (has_zt)
            hipLaunchKernelGGL((k_main_mfma<true>), dim3(2, 64, 16), dim3(256),
                               0, stream, xf, w0f, w1f, w2f, zadj, zadjT,
                               B0, B1, B2, W3, B3, outT);
        else
            hipLaunchKernelGGL((k_main_mfma<false>), dim3(2, 64, 16), dim3(256),
                               0, stream, xf, w0f, w1f, w2f, zadj, zadjT,
                               B0, B1, B2, W3, B3, outT);
        hipLaunchKernelGGL(k_outT, dim3(8, S), dim3(256), 0, stream, outT, out);
    } else {
        hipLaunchKernelGGL(k_zadjprep, dim3(256), dim3(256), 0, stream,
                           z, zadj, (float*)nullptr, x, W0, W1, W2,
                           (uint4*)nullptr, (uint4*)nullptr, (uint4*)nullptr,
                           (uint4*)nullptr);
        float* op = has_oT ? outT : out;
        const int o_sS = has_oT ? (64 * 512) : 64;
        const int o_cS = has_oT ? 512 : 1;
        const int o_bS = has_oT ? 1 : 4096;
        hipLaunchKernelGGL(k_main_valu, dim3(D, S), dim3(256), 0, stream,
                           x, zadj, W0, B0, W1, B1, W2, B2, W3, B3,
                           op, o_sS, o_cS, o_bS);
        if (has_oT)
            hipLaunchKernelGGL(k_outT, dim3(8, S), dim3(256), 0, stream, outT, out);
    }
}

// Round 11
// 216.797 us; speedup vs baseline: 1.1018x; 1.1018x over previous
//
#include <hip/hip_runtime.h>
#include <math.h>

#define D 64
#define S 64
#define BSZ 512
#define LTW 2016
#define ZROW 6112
#define OUT0_SIZE (BSZ * S * D)   // 2097152 floats
#define ZADJ_OFF  OUT0_SIZE

typedef float    f32x4 __attribute__((ext_vector_type(4)));
typedef _Float16 f16x8 __attribute__((ext_vector_type(8)));
typedef _Float16 f16x2 __attribute__((ext_vector_type(2)));

union V8 { f16x8 v; f16x2 h2[4]; uint4 u; };

__device__ __forceinline__ f16x2 pkrtz(float a, float b) {
    return __builtin_bit_cast(f16x2, __builtin_amdgcn_cvt_pkrtz(a, b));
}
__device__ __forceinline__ f16x8 relu8(f16x8 a) {
#if __has_builtin(__builtin_elementwise_max)
    return __builtin_elementwise_max(a, (f16x8)0);   // v_pk_max_f16 x4
#else
    f16x8 r;
#pragma unroll
    for (int i = 0; i < 8; ++i) r[i] = a[i] > (_Float16)0 ? a[i] : (_Float16)0;
    return r;
#endif
}

// ---------------------------------------------------------------------------
// k_zadjprep: blocks 0..255 -> z_adj (s = blk>>2, jt = blk&3), plus
//             transposed zadjT[s][j][i] when zt != nullptr.
//             blocks 256..319 -> fragment prep for channel c = blk-256.
// ---------------------------------------------------------------------------
__global__ __launch_bounds__(256) void k_zadjprep(
    const float* __restrict__ z, float* __restrict__ zadj,
    float* __restrict__ zt,
    const float* __restrict__ x,
    const float* __restrict__ W0, const float* __restrict__ W1,
    const float* __restrict__ W2,
    uint4* __restrict__ w0f, uint4* __restrict__ w1f,
    uint4* __restrict__ w2f, uint4* __restrict__ xf) {
    __shared__ float zp[4096];
    __shared__ float zlt[4160];   // 64 x 65 (padded)
    __shared__ float T[1280];     // 64 x 20 (16 used, padded)
    const int blk = blockIdx.x;
    const int tid = threadIdx.x;

    if (blk < 256) {
        const int s = blk >> 2, jt = blk & 3;
        const float* zs = z + (size_t)s * ZROW;
        const f32x4 zero4 = {0.0f, 0.0f, 0.0f, 0.0f};
#pragma unroll
        for (int rep = 0; rep < 4; ++rep) {
            int idx = (tid + rep * 256) * 4;
            *(f32x4*)&zp[idx] = *(const f32x4*)&zs[LTW + idx];   // dwordx4
            *(f32x4*)&zlt[idx] = zero4;
        }
        if (tid < 16) *(f32x4*)&zlt[4096 + tid * 4] = zero4;
        __syncthreads();
        for (int k = tid; k < LTW; k += 256) {
            float kf = (float)k;
            int r = (int)((1.0f + sqrtf(1.0f + 8.0f * kf)) * 0.5f);
            while (r * (r - 1) / 2 > k) --r;
            while ((r + 1) * r / 2 <= k) ++r;
            int t = k - r * (r - 1) / 2;
            zlt[r * 65 + t] = zs[k];
        }
        __syncthreads();
        // stage 1: T[r][jj] = sum_t zlt[r][t] * zp[t][jt*16+jj], 4 jj/thread
        const int rr = tid & 63, wj = (tid >> 6) * 4;
        {
            f32x4 acc = {0.0f, 0.0f, 0.0f, 0.0f};
#pragma unroll 8
            for (int t = 0; t < 64; ++t) {
                float zl = zlt[rr * 65 + t];                       // 2-way, free
                f32x4 zpv = *(const f32x4*)&zp[t * 64 + jt * 16 + wj]; // bcast
#pragma unroll
                for (int q = 0; q < 4; ++q) acc[q] = fmaf(zl, zpv[q], acc[q]);
            }
            *(f32x4*)&T[rr * 20 + wj] = acc;
        }
        __syncthreads();
        // stage 2: zadj[i][j] = sum_r zp[r][i] * T[r][jj], 4 jj/thread
        {
            const int i = rr;
            f32x4 acc = {0.0f, 0.0f, 0.0f, 0.0f};
#pragma unroll 8
            for (int r = 0; r < 64; ++r) {
                float zv = zp[r * 64 + i];                         // 2-way, free
                f32x4 tv = *(const f32x4*)&T[r * 20 + wj];         // bcast
#pragma unroll
                for (int q = 0; q < 4; ++q) acc[q] = fmaf(zv, tv[q], acc[q]);
            }
            *(f32x4*)&zadj[(size_t)s * 4096 + i * 64 + jt * 16 + wj] = acc;
            if (zt) {
#pragma unroll
                for (int q = 0; q < 4; ++q)
                    zt[(size_t)s * 4096 + (jt * 16 + wj + q) * 64 + i] = acc[q];
            }
        }
    } else {
        const int c = blk - 256;
        const int sl = tid >> 6, ln = tid & 63;
        const int q = ln >> 4, l15 = ln & 15;
        // --- W0 A-frags (16x16x32 f16): A[m][k=ks*32+q*8+j]
        {
            int Mt = sl >> 1, ks = sl & 1;
            const float* src = W0 + c * 2048 + (Mt * 16 + l15) * 64 + ks * 32 + q * 8;
            V8 hv;
#pragma unroll
            for (int j = 0; j < 8; ++j) hv.v[j] = (_Float16)src[j];
            w0f[(size_t)(c * 4 + sl) * 64 + ln] = hv.u;
        }
        // --- W1/W2 A-frags (16x16x32 f16, PERMUTED K): slot j -> k=(j>>2)*16+q*4+(j&3)
        {
            const float* Wsrc = (sl < 2) ? W1 : W2;
            uint4* dstb = (sl < 2) ? w1f : w2f;
            int Mt = sl & 1;
            const float* srow = Wsrc + c * 1024 + (Mt * 16 + l15) * 32;
            V8 hv;
#pragma unroll
            for (int j = 0; j < 8; ++j) {
                int k = ((j >> 2) << 4) + q * 4 + (j & 3);
                hv.v[j] = (_Float16)srow[k];
            }
            dstb[(size_t)(c * 2 + Mt) * 64 + ln] = hv.u;
        }
        // --- x B-frags (16x16x32 f16): B[k=ks*32+q*8+j][n=bt*16+l15]
        if (tid < 64) {
            int f = c * 64 + tid;
            int fln = f & 63, ks = (f >> 6) & 1, bt = f >> 7;
            int n = bt * 16 + (fln & 15), i0 = ks * 32 + (fln >> 4) * 8;
            const float* src = x + n * 64 + i0;
            V8 hv;
#pragma unroll
            for (int j = 0; j < 8; ++j) hv.v[j] = (_Float16)src[j];
            xf[f] = hv.u;
        }
    }
}

// ---------------------------------------------------------------------------
// k_main_mfma: fused 4-layer per-channel MLP. Grid (bh=2, c=64, sg=16);
// ALL global loads (weights, x-frags, biases, 4 s of z) hoisted to the
// prologue -> the s-loop is pure MFMA+VALU+store. 8 MFMA/Nt, in-lane
// transitions. Stores staged to outT (s,c,b), coalesced 256B/wave.
// __launch_bounds__(256,3): measured VGPR=84, no spill. DO NOT raise to
// (256,4) — round 10 showed it forces a 333 MB/dispatch scratch spill.
// DO NOT scatter-store direct (b,s,c) — round 9 showed 5x write amplification.
// ---------------------------------------------------------------------------
template <bool ZT>
__global__ __launch_bounds__(256, 3) void k_main_mfma(
    const uint4* __restrict__ xf, const uint4* __restrict__ w0f,
    const uint4* __restrict__ w1f, const uint4* __restrict__ w2f,
    const float* __restrict__ zadj, const float* __restrict__ zadjT,
    const float* __restrict__ B0, const float* __restrict__ B1,
    const float* __restrict__ B2, const float* __restrict__ W3,
    const float* __restrict__ B3, float* __restrict__ outT) {
    const int bh = blockIdx.x;              // b-half (256 b's)
    const int c = blockIdx.y, sg = blockIdx.z;
    const int tid = threadIdx.x;
    const int wave = tid >> 6, lane = tid & 63;
    const int quad = lane >> 4;
    const int btbase = bh * 16 + wave * 4;  // 16-wide b-tiles

    // ---- hoisted channel weights
    V8 a0[2][2];                             // [Mt][ks]
#pragma unroll
    for (int Mt = 0; Mt < 2; ++Mt)
#pragma unroll
        for (int ks = 0; ks < 2; ++ks)
            a0[Mt][ks].u = w0f[(size_t)(c * 4 + Mt * 2 + ks) * 64 + lane];
    V8 a1[2], a2[2];                         // [Mt], permuted-K
#pragma unroll
    for (int Mt = 0; Mt < 2; ++Mt) {
        a1[Mt].u = w1f[(size_t)(c * 2 + Mt) * 64 + lane];
        a2[Mt].u = w2f[(size_t)(c * 2 + Mt) * 64 + lane];
    }
    // ---- hoisted x fragments (s-invariant)
    V8 xv[4][2];                             // [Nt][ks]
#pragma unroll
    for (int Nt = 0; Nt < 4; ++Nt)
#pragma unroll
        for (int ks = 0; ks < 2; ++ks)
            xv[Nt][ks].u = xf[(size_t)((btbase + Nt) * 2 + ks) * 64 + lane];
    // ---- biases / w3 (per-lane rows o = Mt*16 + quad*4 + r)
    f32x4 b0v[2], b1v[2], b2v[2], w3v[2];
#pragma unroll
    for (int Mt = 0; Mt < 2; ++Mt) {
        int off = c * 32 + Mt * 16 + quad * 4;
        b0v[Mt] = *(const f32x4*)(B0 + off);
        b1v[Mt] = *(const f32x4*)(B1 + off);
        b2v[Mt] = *(const f32x4*)(B2 + off);
        w3v[Mt] = *(const f32x4*)(W3 + off);
    }
    const float b3v = B3[c];

    // ---- hoist ALL 4 s of z: load (overlapped) then cvt to f16 pairs
    f16x2 zvh[4][2][4];                      // [it][ks][t]
#pragma unroll
    for (int it = 0; it < 4; ++it) {
        const int s = sg * 4 + it;
        if (ZT) {
            const f32x4* ztp = (const f32x4*)(zadjT + (size_t)s * 4096 + c * 64);
            f32x4 zq0 = ztp[quad * 2];
            f32x4 zq1 = ztp[quad * 2 + 1];
            f32x4 zq2 = ztp[8 + quad * 2];
            f32x4 zq3 = ztp[8 + quad * 2 + 1];
            zvh[it][0][0] = pkrtz(zq0[0], zq0[1]);
            zvh[it][0][1] = pkrtz(zq0[2], zq0[3]);
            zvh[it][0][2] = pkrtz(zq1[0], zq1[1]);
            zvh[it][0][3] = pkrtz(zq1[2], zq1[3]);
            zvh[it][1][0] = pkrtz(zq2[0], zq2[1]);
            zvh[it][1][1] = pkrtz(zq2[2], zq2[3]);
            zvh[it][1][2] = pkrtz(zq3[0], zq3[1]);
            zvh[it][1][3] = pkrtz(zq3[2], zq3[3]);
        } else {
#pragma unroll
            for (int ks = 0; ks < 2; ++ks) {
                const float* zp = zadj + (size_t)s * 4096 + (ks * 32 + quad * 8) * 64 + c;
                float zv[8];
#pragma unroll
                for (int j = 0; j < 8; ++j) zv[j] = zp[j * 64];
#pragma unroll
                for (int t = 0; t < 4; ++t)
                    zvh[it][ks][t] = pkrtz(zv[2 * t], zv[2 * t + 1]);
            }
        }
    }

#pragma unroll 1
    for (int it = 0; it < 4; ++it) {
        const int s = sg * 4 + it;
        // ---- scale layer-0 A by z (A[m][k] *= z[k])
        V8 a0s[2][2];
#pragma unroll
        for (int Mt = 0; Mt < 2; ++Mt)
#pragma unroll
            for (int ks = 0; ks < 2; ++ks)
#pragma unroll
                for (int t = 0; t < 4; ++t)
                    a0s[Mt][ks].h2[t] = a0[Mt][ks].h2[t] * zvh[it][ks][t];

        float red[4];
#pragma unroll
        for (int Nt = 0; Nt < 4; ++Nt) {
            // ---------- layer 0 ----------
            f32x4 acc0[2] = {b0v[0], b0v[1]};
#pragma unroll
            for (int ks = 0; ks < 2; ++ks)
#pragma unroll
                for (int Mt = 0; Mt < 2; ++Mt)
                    acc0[Mt] = __builtin_amdgcn_mfma_f32_16x16x32_f16(
                        a0s[Mt][ks].v, xv[Nt][ks].v, acc0[Mt], 0, 0, 0);
            // ---------- transition 0->1 (pkrtz then packed relu) ----------
            V8 bb;
            bb.h2[0] = pkrtz(acc0[0][0], acc0[0][1]);
            bb.h2[1] = pkrtz(acc0[0][2], acc0[0][3]);
            bb.h2[2] = pkrtz(acc0[1][0], acc0[1][1]);
            bb.h2[3] = pkrtz(acc0[1][2], acc0[1][3]);
            bb.v = relu8(bb.v);
            // ---------- layer 1 ----------
            f32x4 acc1[2] = {b1v[0], b1v[1]};
#pragma unroll
            for (int Mt = 0; Mt < 2; ++Mt)
                acc1[Mt] = __builtin_amdgcn_mfma_f32_16x16x32_f16(
                    a1[Mt].v, bb.v, acc1[Mt], 0, 0, 0);
            // ---------- transition 1->2 ----------
            V8 cc;
            cc.h2[0] = pkrtz(acc1[0][0], acc1[0][1]);
            cc.h2[1] = pkrtz(acc1[0][2], acc1[0][3]);
            cc.h2[2] = pkrtz(acc1[1][0], acc1[1][1]);
            cc.h2[3] = pkrtz(acc1[1][2], acc1[1][3]);
            cc.v = relu8(cc.v);
            // ---------- layer 2 ----------
            f32x4 acc2[2] = {b2v[0], b2v[1]};
#pragma unroll
            for (int Mt = 0; Mt < 2; ++Mt)
                acc2[Mt] = __builtin_amdgcn_mfma_f32_16x16x32_f16(
                    a2[Mt].v, cc.v, acc2[Mt], 0, 0, 0);
            // ---------- layer 3 partial: relu(acc2) . w3 ----------
            float p = 0.0f;
#pragma unroll
            for (int Mt = 0; Mt < 2; ++Mt)
#pragma unroll
                for (int r = 0; r < 4; ++r)
                    p = fmaf(w3v[Mt][r], fmaxf(acc2[Mt][r], 0.0f), p);
            p += __shfl_xor(p, 16, 64);
            p += __shfl_xor(p, 32, 64);
            red[Nt] = p;
        }
        float outv = (quad & 2) ? ((quad & 1) ? red[3] : red[2])
                                : ((quad & 1) ? red[1] : red[0]);
        outv += b3v;
        // coalesced 256B per wave into outT (s,c,b)
        outT[((size_t)s * 64 + c) * 512 + bh * 256 + tid] = outv;
    }
}

// ---------------------------------------------------------------------------
// Fallback VALU kernel (round-2 proven path).
// ---------------------------------------------------------------------------
__global__ __launch_bounds__(256, 3) void k_main_valu(
    const float* __restrict__ xsrc, const float* __restrict__ zadj,
    const float* __restrict__ W0, const float* __restrict__ B0,
    const float* __restrict__ W1, const float* __restrict__ B1,
    const float* __restrict__ W2, const float* __restrict__ B2,
    const float* __restrict__ W3, const float* __restrict__ B3,
    float* __restrict__ outp, int o_sS, int o_cS, int o_bS) {
    const int c = blockIdx.x;
    const int s = blockIdx.y;
    const int lane = threadIdx.x & 63;
    const int wave = threadIdx.x >> 6;

    const float* w0c = W0 + c * 2048;
    const float* w1c = W1 + c * 1024;
    const float* w2c = W2 + c * 1024;
    const float* w3c = W3 + c * 32;
    const float* b0c = B0 + c * 32;
    const float* b1c = B1 + c * 32;
    const float* b2c = B2 + c * 32;
    const float b3v = B3[c];
    const float* zc = zadj + s * 4096 + c;

#pragma unroll 1
    for (int bc = 0; bc < 2; ++bc) {
        const int b = wave * 128 + bc * 64 + lane;
        float h1[32], h2[32];
#pragma unroll
        for (int o = 0; o < 32; ++o) h1[o] = b0c[o];
#pragma unroll 8
        for (int i = 0; i < 64; ++i) {
            float hi = zc[i * 64] * xsrc[b * 64 + i];
#pragma unroll
            for (int o = 0; o < 32; ++o) h1[o] = fmaf(w0c[o * 64 + i], hi, h1[o]);
        }
#pragma unroll
        for (int o = 0; o < 32; ++o) { h1[o] = fmaxf(h1[o], 0.0f); h2[o] = b1c[o]; }
#pragma unroll 8
        for (int j = 0; j < 32; ++j) {
            float v = h1[j];
#pragma unroll
            for (int o = 0; o < 32; ++o) h2[o] = fmaf(w1c[o * 32 + j], v, h2[o]);
        }
#pragma unroll
        for (int o = 0; o < 32; ++o) { h2[o] = fmaxf(h2[o], 0.0f); h1[o] = b2c[o]; }
#pragma unroll 8
        for (int j = 0; j < 32; ++j) {
            float v = h2[j];
#pragma unroll
            for (int o = 0; o < 32; ++o) h1[o] = fmaf(w2c[o * 32 + j], v, h1[o]);
        }
        float a = b3v;
#pragma unroll
        for (int j = 0; j < 32; ++j) a = fmaf(w3c[j], fmaxf(h1[j], 0.0f), a);
        outp[s * o_sS + c * o_cS + b * o_bS] = a;
    }
}

// ---------------------------------------------------------------------------
// k_outT: transpose outT (s,c,b) -> out (b,s,c). dwordx4 global both sides.
// ---------------------------------------------------------------------------
__global__ __launch_bounds__(256) void k_outT(const float* __restrict__ outT,
                                              float* __restrict__ out) {
    __shared__ float tile[64 * 65];
    const int bt = blockIdx.x;   // 8 b-tiles
    const int s = blockIdx.y;    // 64
    const int tid = threadIdx.x;
    const int r16 = tid >> 4, q4 = (tid & 15) * 4;
#pragma unroll
    for (int rep = 0; rep < 4; ++rep) {
        int crow = rep * 16 + r16;
        f32x4 v = *(const f32x4*)&outT[(s * 64 + crow) * 512 + bt * 64 + q4];
#pragma unroll
        for (int i = 0; i < 4; ++i) tile[crow * 65 + q4 + i] = v[i];
    }
    __syncthreads();
#pragma unroll
    for (int rep = 0; rep < 4; ++rep) {
        int brow = rep * 16 + r16;
        f32x4 v;
#pragma unroll
        for (int i = 0; i < 4; ++i) v[i] = tile[(q4 + i) * 65 + brow];
        *(f32x4*)&out[(bt * 64 + brow) * 4096 + s * 64 + q4] = v;
    }
}

extern "C" void kernel_launch(void* const* d_in, const int* in_sizes, int n_in,
                              void* d_out, int out_size, void* d_ws, size_t ws_size,
                              hipStream_t stream) {
    const float* x  = (const float*)d_in[0];
    const float* z  = (const float*)d_in[1];
    const float* W0 = (const float*)d_in[2];
    const float* B0 = (const float*)d_in[3];
    const float* W1 = (const float*)d_in[4];
    const float* B1 = (const float*)d_in[5];
    const float* W2 = (const float*)d_in[6];
    const float* B2 = (const float*)d_in[7];
    const float* W3 = (const float*)d_in[8];
    const float* B3 = (const float*)d_in[9];

    float* out  = (float*)d_out;
    float* zadj = out + ZADJ_OFF;

    // workspace: outT | xf | w0f | w1f | w2f | zadjT
    const size_t OT_B  = (size_t)S * D * BSZ * sizeof(float); // 8388608
    const size_t XF_B  = 4096 * 16;                           // 65536
    const size_t W0F_B = (size_t)64 * 4 * 64 * 16;            // 262144
    const size_t W1F_B = (size_t)64 * 2 * 64 * 16;            // 131072
    const size_t W2F_B = W1F_B;
    const size_t ZT_B  = (size_t)S * 4096 * sizeof(float);    // 1048576
    const size_t FRAG_END = OT_B + XF_B + W0F_B + W1F_B + W2F_B;
    const bool has_oT   = ws_size >= OT_B;
    const bool has_frag = ws_size >= FRAG_END;
    const bool has_zt   = ws_size >= FRAG_END + ZT_B;

    char* wsb = (char*)d_ws;
    float* outT  = (float*)wsb;
    uint4* xf    = (uint4*)(wsb + OT_B);
    uint4* w0f   = (uint4*)(wsb + OT_B + XF_B);
    uint4* w1f   = (uint4*)(wsb + OT_B + XF_B + W0F_B);
    uint4* w2f   = (uint4*)(wsb + OT_B + XF_B + W0F_B + W1F_B);
    float* zadjT = (float*)(wsb + FRAG_END);

    if (has_frag) {
        hipLaunchKernelGGL(k_zadjprep, dim3(320), dim3(256), 0, stream,
                           z, zadj, has_zt ? zadjT : (float*)nullptr,
                           x, W0, W1, W2, w0f, w1f, w2f, xf);
        if (has_zt)
            hipLaunchKernelGGL((k_main_mfma<true>), dim3(2, 64, 16), dim3(256),
                               0, stream, xf, w0f, w1f, w2f, zadj, zadjT,
                               B0, B1, B2, W3, B3, outT);
        else
            hipLaunchKernelGGL((k_main_mfma<false>), dim3(2, 64, 16), dim3(256),
                               0, stream, xf, w0f, w1f, w2f, zadj, zadjT,
                               B0, B1, B2, W3, B3, outT);
        hipLaunchKernelGGL(k_outT, dim3(8, S), dim3(256), 0, stream, outT, out);
    } else {
        hipLaunchKernelGGL(k_zadjprep, dim3(256), dim3(256), 0, stream,
                           z, zadj, (float*)nullptr, x, W0, W1, W2,
                           (uint4*)nullptr, (uint4*)nullptr, (uint4*)nullptr,
                           (uint4*)nullptr);
        float* op = has_oT ? outT : out;
        const int o_sS = has_oT ? (64 * 512) : 64;
        const int o_cS = has_oT ? 512 : 1;
        const int o_bS = has_oT ? 1 : 4096;
        hipLaunchKernelGGL(k_main_valu, dim3(D, S), dim3(256), 0, stream,
                           x, zadj, W0, B0, W1, B1, W2, B2, W3, B3,
                           op, o_sS, o_cS, o_bS);
        if (has_oT)
            hipLaunchKernelGGL(k_outT, dim3(8, S), dim3(256), 0, stream, outT, out);
    }
}

// Round 12
// 108.885 us; speedup vs baseline: 2.1937x; 1.9911x over previous
//
#include <hip/hip_runtime.h>
#include <math.h>

#define D 64
#define S 64
#define BSZ 512
#define LTW 2016
#define ZROW 6112
#define OUT0_SIZE (BSZ * S * D)   // 2097152 floats
#define ZADJ_OFF  OUT0_SIZE

typedef float    f32x4 __attribute__((ext_vector_type(4)));
typedef _Float16 f16x8 __attribute__((ext_vector_type(8)));
typedef _Float16 f16x2 __attribute__((ext_vector_type(2)));

union V8 { f16x8 v; f16x2 h2[4]; uint4 u; };

__device__ __forceinline__ f16x2 pkrtz(float a, float b) {
    return __builtin_bit_cast(f16x2, __builtin_amdgcn_cvt_pkrtz(a, b));
}
__device__ __forceinline__ f16x8 relu8(f16x8 a) {
#if __has_builtin(__builtin_elementwise_max)
    return __builtin_elementwise_max(a, (f16x8)0);   // v_pk_max_f16 x4
#else
    f16x8 r;
#pragma unroll
    for (int i = 0; i < 8; ++i) r[i] = a[i] > (_Float16)0 ? a[i] : (_Float16)0;
    return r;
#endif
}

// ---------------------------------------------------------------------------
// k_zadjprep: blocks 0..255 -> z_adj (s = blk>>2, jt = blk&3), plus
//             transposed zadjT[s][j][i] when zt != nullptr.
//             blocks 256..319 -> fragment prep for channel c = blk-256.
// ---------------------------------------------------------------------------
__global__ __launch_bounds__(256) void k_zadjprep(
    const float* __restrict__ z, float* __restrict__ zadj,
    float* __restrict__ zt,
    const float* __restrict__ x,
    const float* __restrict__ W0, const float* __restrict__ W1,
    const float* __restrict__ W2,
    uint4* __restrict__ w0f, uint4* __restrict__ w1f,
    uint4* __restrict__ w2f, uint4* __restrict__ xf) {
    __shared__ float zp[4096];
    __shared__ float zlt[4160];   // 64 x 65 (padded)
    __shared__ float T[1280];     // 64 x 20 (16 used, padded)
    const int blk = blockIdx.x;
    const int tid = threadIdx.x;

    if (blk < 256) {
        const int s = blk >> 2, jt = blk & 3;
        const float* zs = z + (size_t)s * ZROW;
        const f32x4 zero4 = {0.0f, 0.0f, 0.0f, 0.0f};
#pragma unroll
        for (int rep = 0; rep < 4; ++rep) {
            int idx = (tid + rep * 256) * 4;
            *(f32x4*)&zp[idx] = *(const f32x4*)&zs[LTW + idx];   // dwordx4
            *(f32x4*)&zlt[idx] = zero4;
        }
        if (tid < 16) *(f32x4*)&zlt[4096 + tid * 4] = zero4;
        __syncthreads();
        for (int k = tid; k < LTW; k += 256) {
            float kf = (float)k;
            int r = (int)((1.0f + sqrtf(1.0f + 8.0f * kf)) * 0.5f);
            while (r * (r - 1) / 2 > k) --r;
            while ((r + 1) * r / 2 <= k) ++r;
            int t = k - r * (r - 1) / 2;
            zlt[r * 65 + t] = zs[k];
        }
        __syncthreads();
        // stage 1: T[r][jj] = sum_t zlt[r][t] * zp[t][jt*16+jj], 4 jj/thread
        const int rr = tid & 63, wj = (tid >> 6) * 4;
        {
            f32x4 acc = {0.0f, 0.0f, 0.0f, 0.0f};
#pragma unroll 8
            for (int t = 0; t < 64; ++t) {
                float zl = zlt[rr * 65 + t];                       // 2-way, free
                f32x4 zpv = *(const f32x4*)&zp[t * 64 + jt * 16 + wj]; // bcast
#pragma unroll
                for (int q = 0; q < 4; ++q) acc[q] = fmaf(zl, zpv[q], acc[q]);
            }
            *(f32x4*)&T[rr * 20 + wj] = acc;
        }
        __syncthreads();
        // stage 2: zadj[i][j] = sum_r zp[r][i] * T[r][jj], 4 jj/thread
        {
            const int i = rr;
            f32x4 acc = {0.0f, 0.0f, 0.0f, 0.0f};
#pragma unroll 8
            for (int r = 0; r < 64; ++r) {
                float zv = zp[r * 64 + i];                         // 2-way, free
                f32x4 tv = *(const f32x4*)&T[r * 20 + wj];         // bcast
#pragma unroll
                for (int q = 0; q < 4; ++q) acc[q] = fmaf(zv, tv[q], acc[q]);
            }
            *(f32x4*)&zadj[(size_t)s * 4096 + i * 64 + jt * 16 + wj] = acc;
            if (zt) {
#pragma unroll
                for (int q = 0; q < 4; ++q)
                    zt[(size_t)s * 4096 + (jt * 16 + wj + q) * 64 + i] = acc[q];
            }
        }
    } else {
        const int c = blk - 256;
        const int sl = tid >> 6, ln = tid & 63;
        const int q = ln >> 4, l15 = ln & 15;
        // --- W0 A-frags (16x16x32 f16): A[m][k=ks*32+q*8+j]
        {
            int Mt = sl >> 1, ks = sl & 1;
            const float* src = W0 + c * 2048 + (Mt * 16 + l15) * 64 + ks * 32 + q * 8;
            V8 hv;
#pragma unroll
            for (int j = 0; j < 8; ++j) hv.v[j] = (_Float16)src[j];
            w0f[(size_t)(c * 4 + sl) * 64 + ln] = hv.u;
        }
        // --- W1/W2 A-frags (16x16x32 f16, PERMUTED K): slot j -> k=(j>>2)*16+q*4+(j&3)
        {
            const float* Wsrc = (sl < 2) ? W1 : W2;
            uint4* dstb = (sl < 2) ? w1f : w2f;
            int Mt = sl & 1;
            const float* srow = Wsrc + c * 1024 + (Mt * 16 + l15) * 32;
            V8 hv;
#pragma unroll
            for (int j = 0; j < 8; ++j) {
                int k = ((j >> 2) << 4) + q * 4 + (j & 3);
                hv.v[j] = (_Float16)srow[k];
            }
            dstb[(size_t)(c * 2 + Mt) * 64 + ln] = hv.u;
        }
        // --- x B-frags (16x16x32 f16): B[k=ks*32+q*8+j][n=bt*16+l15]
        if (tid < 64) {
            int f = c * 64 + tid;
            int fln = f & 63, ks = (f >> 6) & 1, bt = f >> 7;
            int n = bt * 16 + (fln & 15), i0 = ks * 32 + (fln >> 4) * 8;
            const float* src = x + n * 64 + i0;
            V8 hv;
#pragma unroll
            for (int j = 0; j < 8; ++j) hv.v[j] = (_Float16)src[j];
            xf[f] = hv.u;
        }
    }
}

// ---------------------------------------------------------------------------
// k_main_mfma: fused 4-layer per-channel MLP. Grid (bh=2, c=64, sg=16);
// weights + x-frags + biases hoisted in registers (ONLY constant-indexed
// arrays); z loaded & converted INSIDE the s-loop so every register array
// index is a compile-time constant.
//   DO NOT hoist z into zvh[4][..] indexed by the s-loop variable —
//   rounds 9-11 showed runtime-indexed register arrays lower to scratch /
//   select machinery: k_main 140 µs vs <40 µs, VALU ~5x.
//   DO NOT raise __launch_bounds__ to (256,4) — round 10: 333 MB spill.
//   DO NOT scatter-store direct (b,s,c) — round 9: 5x write amplification.
// 8 MFMA/Nt, in-lane transitions (pkrtz + pk_max). Stores staged to outT.
// ---------------------------------------------------------------------------
template <bool ZT>
__global__ __launch_bounds__(256, 3) void k_main_mfma(
    const uint4* __restrict__ xf, const uint4* __restrict__ w0f,
    const uint4* __restrict__ w1f, const uint4* __restrict__ w2f,
    const float* __restrict__ zadj, const float* __restrict__ zadjT,
    const float* __restrict__ B0, const float* __restrict__ B1,
    const float* __restrict__ B2, const float* __restrict__ W3,
    const float* __restrict__ B3, float* __restrict__ outT) {
    const int bh = blockIdx.x;              // b-half (256 b's)
    const int c = blockIdx.y, sg = blockIdx.z;
    const int tid = threadIdx.x;
    const int wave = tid >> 6, lane = tid & 63;
    const int quad = lane >> 4;
    const int btbase = bh * 16 + wave * 4;  // 16-wide b-tiles

    // ---- hoisted channel weights
    V8 a0[2][2];                             // [Mt][ks]
#pragma unroll
    for (int Mt = 0; Mt < 2; ++Mt)
#pragma unroll
        for (int ks = 0; ks < 2; ++ks)
            a0[Mt][ks].u = w0f[(size_t)(c * 4 + Mt * 2 + ks) * 64 + lane];
    V8 a1[2], a2[2];                         // [Mt], permuted-K
#pragma unroll
    for (int Mt = 0; Mt < 2; ++Mt) {
        a1[Mt].u = w1f[(size_t)(c * 2 + Mt) * 64 + lane];
        a2[Mt].u = w2f[(size_t)(c * 2 + Mt) * 64 + lane];
    }
    // ---- hoisted x fragments (s-invariant)
    V8 xv[4][2];                             // [Nt][ks]
#pragma unroll
    for (int Nt = 0; Nt < 4; ++Nt)
#pragma unroll
        for (int ks = 0; ks < 2; ++ks)
            xv[Nt][ks].u = xf[(size_t)((btbase + Nt) * 2 + ks) * 64 + lane];
    // ---- biases / w3 (per-lane rows o = Mt*16 + quad*4 + r)
    f32x4 b0v[2], b1v[2], b2v[2], w3v[2];
#pragma unroll
    for (int Mt = 0; Mt < 2; ++Mt) {
        int off = c * 32 + Mt * 16 + quad * 4;
        b0v[Mt] = *(const f32x4*)(B0 + off);
        b1v[Mt] = *(const f32x4*)(B1 + off);
        b2v[Mt] = *(const f32x4*)(B2 + off);
        w3v[Mt] = *(const f32x4*)(W3 + off);
    }
    const float b3v = B3[c];

#pragma unroll 1
    for (int it = 0; it < 4; ++it) {
        const int s = sg * 4 + it;
        // ---- z (diag) for k = ks*32 + quad*8 + j, as f16 pairs (per-iter:
        //      all register-array indices below are compile-time constants)
        f16x2 zvh[2][4];
        if (ZT) {
            const f32x4* ztp = (const f32x4*)(zadjT + (size_t)s * 4096 + c * 64);
            f32x4 zq0 = ztp[quad * 2];
            f32x4 zq1 = ztp[quad * 2 + 1];
            f32x4 zq2 = ztp[8 + quad * 2];
            f32x4 zq3 = ztp[8 + quad * 2 + 1];
            zvh[0][0] = pkrtz(zq0[0], zq0[1]);
            zvh[0][1] = pkrtz(zq0[2], zq0[3]);
            zvh[0][2] = pkrtz(zq1[0], zq1[1]);
            zvh[0][3] = pkrtz(zq1[2], zq1[3]);
            zvh[1][0] = pkrtz(zq2[0], zq2[1]);
            zvh[1][1] = pkrtz(zq2[2], zq2[3]);
            zvh[1][2] = pkrtz(zq3[0], zq3[1]);
            zvh[1][3] = pkrtz(zq3[2], zq3[3]);
        } else {
#pragma unroll
            for (int ks = 0; ks < 2; ++ks) {
                const float* zp = zadj + (size_t)s * 4096 + (ks * 32 + quad * 8) * 64 + c;
                float zv[8];
#pragma unroll
                for (int j = 0; j < 8; ++j) zv[j] = zp[j * 64];
#pragma unroll
                for (int t = 0; t < 4; ++t)
                    zvh[ks][t] = pkrtz(zv[2 * t], zv[2 * t + 1]);
            }
        }
        // ---- scale layer-0 A by z (A[m][k] *= z[k])
        V8 a0s[2][2];
#pragma unroll
        for (int Mt = 0; Mt < 2; ++Mt)
#pragma unroll
            for (int ks = 0; ks < 2; ++ks)
#pragma unroll
                for (int t = 0; t < 4; ++t)
                    a0s[Mt][ks].h2[t] = a0[Mt][ks].h2[t] * zvh[ks][t];

        float red[4];
#pragma unroll
        for (int Nt = 0; Nt < 4; ++Nt) {
            // ---------- layer 0 ----------
            f32x4 acc0[2] = {b0v[0], b0v[1]};
#pragma unroll
            for (int ks = 0; ks < 2; ++ks)
#pragma unroll
                for (int Mt = 0; Mt < 2; ++Mt)
                    acc0[Mt] = __builtin_amdgcn_mfma_f32_16x16x32_f16(
                        a0s[Mt][ks].v, xv[Nt][ks].v, acc0[Mt], 0, 0, 0);
            // ---------- transition 0->1 (pkrtz then packed relu) ----------
            V8 bb;
            bb.h2[0] = pkrtz(acc0[0][0], acc0[0][1]);
            bb.h2[1] = pkrtz(acc0[0][2], acc0[0][3]);
            bb.h2[2] = pkrtz(acc0[1][0], acc0[1][1]);
            bb.h2[3] = pkrtz(acc0[1][2], acc0[1][3]);
            bb.v = relu8(bb.v);
            // ---------- layer 1 ----------
            f32x4 acc1[2] = {b1v[0], b1v[1]};
#pragma unroll
            for (int Mt = 0; Mt < 2; ++Mt)
                acc1[Mt] = __builtin_amdgcn_mfma_f32_16x16x32_f16(
                    a1[Mt].v, bb.v, acc1[Mt], 0, 0, 0);
            // ---------- transition 1->2 ----------
            V8 cc;
            cc.h2[0] = pkrtz(acc1[0][0], acc1[0][1]);
            cc.h2[1] = pkrtz(acc1[0][2], acc1[0][3]);
            cc.h2[2] = pkrtz(acc1[1][0], acc1[1][1]);
            cc.h2[3] = pkrtz(acc1[1][2], acc1[1][3]);
            cc.v = relu8(cc.v);
            // ---------- layer 2 ----------
            f32x4 acc2[2] = {b2v[0], b2v[1]};
#pragma unroll
            for (int Mt = 0; Mt < 2; ++Mt)
                acc2[Mt] = __builtin_amdgcn_mfma_f32_16x16x32_f16(
                    a2[Mt].v, cc.v, acc2[Mt], 0, 0, 0);
            // ---------- layer 3 partial: relu(acc2) . w3 ----------
            float p = 0.0f;
#pragma unroll
            for (int Mt = 0; Mt < 2; ++Mt)
#pragma unroll
                for (int r = 0; r < 4; ++r)
                    p = fmaf(w3v[Mt][r], fmaxf(acc2[Mt][r], 0.0f), p);
            p += __shfl_xor(p, 16, 64);
            p += __shfl_xor(p, 32, 64);
            red[Nt] = p;
        }
        float outv = (quad & 2) ? ((quad & 1) ? red[3] : red[2])
                                : ((quad & 1) ? red[1] : red[0]);
        outv += b3v;
        // coalesced 256B per wave into outT (s,c,b)
        outT[((size_t)s * 64 + c) * 512 + bh * 256 + tid] = outv;
    }
}

// ---------------------------------------------------------------------------
// Fallback VALU kernel (round-2 proven path).
// ---------------------------------------------------------------------------
__global__ __launch_bounds__(256, 3) void k_main_valu(
    const float* __restrict__ xsrc, const float* __restrict__ zadj,
    const float* __restrict__ W0, const float* __restrict__ B0,
    const float* __restrict__ W1, const float* __restrict__ B1,
    const float* __restrict__ W2, const float* __restrict__ B2,
    const float* __restrict__ W3, const float* __restrict__ B3,
    float* __restrict__ outp, int o_sS, int o_cS, int o_bS) {
    const int c = blockIdx.x;
    const int s = blockIdx.y;
    const int lane = threadIdx.x & 63;
    const int wave = threadIdx.x >> 6;

    const float* w0c = W0 + c * 2048;
    const float* w1c = W1 + c * 1024;
    const float* w2c = W2 + c * 1024;
    const float* w3c = W3 + c * 32;
    const float* b0c = B0 + c * 32;
    const float* b1c = B1 + c * 32;
    const float* b2c = B2 + c * 32;
    const float b3v = B3[c];
    const float* zc = zadj + s * 4096 + c;

#pragma unroll 1
    for (int bc = 0; bc < 2; ++bc) {
        const int b = wave * 128 + bc * 64 + lane;
        float h1[32], h2[32];
#pragma unroll
        for (int o = 0; o < 32; ++o) h1[o] = b0c[o];
#pragma unroll 8
        for (int i = 0; i < 64; ++i) {
            float hi = zc[i * 64] * xsrc[b * 64 + i];
#pragma unroll
            for (int o = 0; o < 32; ++o) h1[o] = fmaf(w0c[o * 64 + i], hi, h1[o]);
        }
#pragma unroll
        for (int o = 0; o < 32; ++o) { h1[o] = fmaxf(h1[o], 0.0f); h2[o] = b1c[o]; }
#pragma unroll 8
        for (int j = 0; j < 32; ++j) {
            float v = h1[j];
#pragma unroll
            for (int o = 0; o < 32; ++o) h2[o] = fmaf(w1c[o * 32 + j], v, h2[o]);
        }
#pragma unroll
        for (int o = 0; o < 32; ++o) { h2[o] = fmaxf(h2[o], 0.0f); h1[o] = b2c[o]; }
#pragma unroll 8
        for (int j = 0; j < 32; ++j) {
            float v = h2[j];
#pragma unroll
            for (int o = 0; o < 32; ++o) h1[o] = fmaf(w2c[o * 32 + j], v, h1[o]);
        }
        float a = b3v;
#pragma unroll
        for (int j = 0; j < 32; ++j) a = fmaf(w3c[j], fmaxf(h1[j], 0.0f), a);
        outp[s * o_sS + c * o_cS + b * o_bS] = a;
    }
}

// ---------------------------------------------------------------------------
// k_outT: transpose outT (s,c,b) -> out (b,s,c). dwordx4 global both sides.
// ---------------------------------------------------------------------------
__global__ __launch_bounds__(256) void k_outT(const float* __restrict__ outT,
                                              float* __restrict__ out) {
    __shared__ float tile[64 * 65];
    const int bt = blockIdx.x;   // 8 b-tiles
    const int s = blockIdx.y;    // 64
    const int tid = threadIdx.x;
    const int r16 = tid >> 4, q4 = (tid & 15) * 4;
#pragma unroll
    for (int rep = 0; rep < 4; ++rep) {
        int crow = rep * 16 + r16;
        f32x4 v = *(const f32x4*)&outT[(s * 64 + crow) * 512 + bt * 64 + q4];
#pragma unroll
        for (int i = 0; i < 4; ++i) tile[crow * 65 + q4 + i] = v[i];
    }
    __syncthreads();
#pragma unroll
    for (int rep = 0; rep < 4; ++rep) {
        int brow = rep * 16 + r16;
        f32x4 v;
#pragma unroll
        for (int i = 0; i < 4; ++i) v[i] = tile[(q4 + i) * 65 + brow];
        *(f32x4*)&out[(bt * 64 + brow) * 4096 + s * 64 + q4] = v;
    }
}

extern "C" void kernel_launch(void* const* d_in, const int* in_sizes, int n_in,
                              void* d_out, int out_size, void* d_ws, size_t ws_size,
                              hipStream_t stream) {
    const float* x  = (const float*)d_in[0];
    const float* z  = (const float*)d_in[1];
    const float* W0 = (const float*)d_in[2];
    const float* B0 = (const float*)d_in[3];
    const float* W1 = (const float*)d_in[4];
    const float* B1 = (const float*)d_in[5];
    const float* W2 = (const float*)d_in[6];
    const float* B2 = (const float*)d_in[7];
    const float* W3 = (const float*)d_in[8];
    const float* B3 = (const float*)d_in[9];

    float* out  = (float*)d_out;
    float* zadj = out + ZADJ_OFF;

    // workspace: outT | xf | w0f | w1f | w2f | zadjT
    const size_t OT_B  = (size_t)S * D * BSZ * sizeof(float); // 8388608
    const size_t XF_B  = 4096 * 16;                           // 65536
    const size_t W0F_B = (size_t)64 * 4 * 64 * 16;            // 262144
    const size_t W1F_B = (size_t)64 * 2 * 64 * 16;            // 131072
    const size_t W2F_B = W1F_B;
    const size_t ZT_B  = (size_t)S * 4096 * sizeof(float);    // 1048576
    const size_t FRAG_END = OT_B + XF_B + W0F_B + W1F_B + W2F_B;
    const bool has_oT   = ws_size >= OT_B;
    const bool has_frag = ws_size >= FRAG_END;
    const bool has_zt   = ws_size >= FRAG_END + ZT_B;

    char* wsb = (char*)d_ws;
    float* outT  = (float*)wsb;
    uint4* xf    = (uint4*)(wsb + OT_B);
    uint4* w0f   = (uint4*)(wsb + OT_B + XF_B);
    uint4* w1f   = (uint4*)(wsb + OT_B + XF_B + W0F_B);
    uint4* w2f   = (uint4*)(wsb + OT_B + XF_B + W0F_B + W1F_B);
    float* zadjT = (float*)(wsb + FRAG_END);

    if (has_frag) {
        hipLaunchKernelGGL(k_zadjprep, dim3(320), dim3(256), 0, stream,
                           z, zadj, has_zt ? zadjT : (float*)nullptr,
                           x, W0, W1, W2, w0f, w1f, w2f, xf);
        if (has_zt)
            hipLaunchKernelGGL((k_main_mfma<true>), dim3(2, 64, 16), dim3(256),
                               0, stream, xf, w0f, w1f, w2f, zadj, zadjT,
                               B0, B1, B2, W3, B3, outT);
        else
            hipLaunchKernelGGL((k_main_mfma<false>), dim3(2, 64, 16), dim3(256),
                               0, stream, xf, w0f, w1f, w2f, zadj, zadjT,
                               B0, B1, B2, W3, B3, outT);
        hipLaunchKernelGGL(k_outT, dim3(8, S), dim3(256), 0, stream, outT, out);
    } else {
        hipLaunchKernelGGL(k_zadjprep, dim3(256), dim3(256), 0, stream,
                           z, zadj, (float*)nullptr, x, W0, W1, W2,
                           (uint4*)nullptr, (uint4*)nullptr, (uint4*)nullptr,
                           (uint4*)nullptr);
        float* op = has_oT ? outT : out;
        const int o_sS = has_oT ? (64 * 512) : 64;
        const int o_cS = has_oT ? 512 : 1;
        const int o_bS = has_oT ? 1 : 4096;
        hipLaunchKernelGGL(k_main_valu, dim3(D, S), dim3(256), 0, stream,
                           x, zadj, W0, B0, W1, B1, W2, B2, W3, B3,
                           op, o_sS, o_cS, o_bS);
        if (has_oT)
            hipLaunchKernelGGL(k_outT, dim3(8, S), dim3(256), 0, stream, outT, out);
    }
}